// Round 13
// baseline (216.514 us; speedup 1.0000x reference)
//
#include <hip/hip_runtime.h>
#include <cstdint>
#include <cstddef>

// MultiHeadAttention R23:
//   attn_mfma unchanged (R22 j-split: 8 waves, 2-way chunk split, -9us).
//   gemm_obt, cast unchanged.
//   gemm_qkv K-LOOP RESTRUCTURED (bitwise-identical math): after the P0
//   vmcnt(4)+barrier the ENTIRE tile t is resident (queue invariant:
//   entering tile t's wait = {t-lo, t-hi, t+1-lo}; <=4 drains t-lo+t-hi).
//   So: hoist ALL 24 fragment ds_reads to right after the wait (latency
//   drains under the q0/q1 MFMA clusters), fuse quadrants into two 32-MFMA
//   super-clusters, and use TWO barriers/tile (was 3): the mid-tile
//   lgkmcnt(0)+barrier orders reads-of-buffer-b before the t+2-lo GLDS
//   overwrite. Stage placement totals unchanged -> same vmcnt accounting.
//   Evidence: qkv = top dispatch at 55.3us (3.45us/K-tile = 8280cy vs
//   ~1400cy countable work, MfmaUtil 17%, nothing saturated); m201 (same
//   tile/waves/LDS) does 1.37us/tile -> schedule-structural gap; reads-
//   after-barrier + extra barrier are the two deficits fixable without
//   touching arithmetic order. VGPR ~240 (capped 256 by launch_bounds;
//   1 block/CU is LDS-bound so no occupancy cost).
// ws layout (bytes):
//   xb @0 [4096][1024] bf16 | wqb @8388608 [3072][1024] | wob @14680064 [1024][1024]
//   Qb @16777216, Kb @25165824: [2][16][2048][64] bf16 (Qb = Q*log2e)
//   Vt @33554432: [2][16][64][2048] bf16 (transposed)
//   CTX @41943040 [4096][1024] bf16
// MFMA 16x16x32_bf16 frags: A[m=lane&15][k=quad*8+i], B[n=lane&15][k=quad*8+i],
// C/D[row=quad*4+reg][col=lane&15]. 16x16x16: k=quad*4+i, same C/D.
// Swapped operands -> D = C^T.

typedef __attribute__((ext_vector_type(8))) short bf16x8;
typedef __attribute__((ext_vector_type(4))) short bf16x4;
typedef __attribute__((ext_vector_type(4))) float f32x4;

#define LOG2E 1.44269504f

#define MFMA16(a, b, c) __builtin_amdgcn_mfma_f32_16x16x32_bf16((a), (b), (c), 0, 0, 0)

// K=16 bf16 MFMA: guard must only run in the DEVICE pass -- __has_builtin
// returns false for amdgcn builtins during hipcc's host pass (R10 lesson).
#if defined(__HIP_DEVICE_COMPILE__)
  #if __has_builtin(__builtin_amdgcn_mfma_f32_16x16x16bf16_1k)
    #define MFMAK16(a, b, c) __builtin_amdgcn_mfma_f32_16x16x16bf16_1k((a), (b), (c), 0, 0, 0)
  #elif __has_builtin(__builtin_amdgcn_mfma_f32_16x16x16_bf16)
    #define MFMAK16(a, b, c) __builtin_amdgcn_mfma_f32_16x16x16_bf16((a), (b), (c), 0, 0, 0)
  #else
    #error "no 16x16x16 bf16 MFMA builtin on device"
  #endif
#else
  #define MFMAK16(a, b, c) (c)   // host pass: parsed, never executed
#endif

#define GLDS16(g, s)                                                        \
  __builtin_amdgcn_global_load_lds(                                         \
      (const __attribute__((address_space(1))) void*)(g),                   \
      (__attribute__((address_space(3))) void*)(s), 16, 0, 0)

// Manual barrier: wait until <= N vector-memory ops outstanding, then barrier.
// ONLY valid when the loop's vmem traffic is exclusively the staged GLDS.
#define ASYNC_BAR(N) asm volatile("s_waitcnt vmcnt(" #N ")\n\ts_barrier" ::: "memory")
#define BAR() asm volatile("s_barrier" ::: "memory")
#define LGKM0() asm volatile("s_waitcnt lgkmcnt(0)" ::: "memory")

// Native 2^x: v_exp_f32 (gfx950 VOP1). Input already in log2 domain.
static __device__ __forceinline__ float exp2_hw(float x) {
  float r;
  asm("v_exp_f32 %0, %1" : "=v"(r) : "v"(x));
  return r;
}
#define EXP2F(x) exp2_hw(x)

static __device__ __forceinline__ unsigned short f2bf(float f) {  // RNE
  unsigned int u = __builtin_bit_cast(unsigned int, f);
  u += 0x7FFFu + ((u >> 16) & 1u);
  return (unsigned short)(u >> 16);
}

// pack two fp32 -> two bf16 (round-nearest) in one u32: 2 add + 1 perm
static __device__ __forceinline__ unsigned int pk2bf(float a, float b) {
  const unsigned int ua = __builtin_bit_cast(unsigned int, a) + 0x8000u;
  const unsigned int ub = __builtin_bit_cast(unsigned int, b) + 0x8000u;
  return __builtin_amdgcn_perm(ub, ua, 0x07060302);
}

// ---------------------------------------------------------------------------
__global__ __launch_bounds__(256) void cast_bf16(const float* __restrict__ x,
                                                 const float* __restrict__ wq,
                                                 const float* __restrict__ wo,
                                                 unsigned short* __restrict__ xb,
                                                 unsigned short* __restrict__ wqb,
                                                 unsigned short* __restrict__ wob)
{
  const int id = blockIdx.x * 256 + threadIdx.x;
  const float* src;
  unsigned short* dst;
  int off;
  if (id < 1048576)               { src = x;  dst = xb;  off = id; }
  else if (id < 1048576 + 786432) { src = wq; dst = wqb; off = id - 1048576; }
  else                            { src = wo; dst = wob; off = id - (1048576 + 786432); }
  float4 v = ((const float4*)src)[off];
  ushort4 o;
  o.x = f2bf(v.x); o.y = f2bf(v.y); o.z = f2bf(v.z); o.w = f2bf(v.w);
  ((ushort4*)dst)[off] = o;
}

// ---------------------------------------------------------------------------
// QKV GEMM R23: 256x256 tile, BK=64, 512 threads = 8 waves (2M x 4N),
// per-wave 128x64 output (acc[8][4] of 16x16 frags).
// LDS 128 KiB: 2 buffers x (A 256x64 | B 256x64) bf16, rows of 128B split
// into 8x16B slots, phys_slot = logical_slot ^ (row & 7)   [FULL 3-bit XOR].
// K-loop: per tile, ONE vmcnt(4)+barrier (tile fully resident), ALL 24
// fragment reads hoisted, 2x 32-MFMA clusters, ONE mid-tile lgkmcnt(0)+
// barrier before the t+2-lo overwrite. Same read set + MFMA order as R12.
// ---------------------------------------------------------------------------
#define MMAC(AF, BF, MS, NS)                                                       \
  do {                                                                             \
    __builtin_amdgcn_s_setprio(1);                                                 \
    if (swapped) {                                                                 \
      _Pragma("unroll")                                                            \
      for (int mt = 0; mt < 4; ++mt)                                               \
        _Pragma("unroll")                                                          \
        for (int nt = 0; nt < 2; ++nt) {                                           \
          acc[(MS)*4+mt][(NS)*2+nt] = MFMA16(BF[nt][0], AF[mt][0], acc[(MS)*4+mt][(NS)*2+nt]); \
          acc[(MS)*4+mt][(NS)*2+nt] = MFMA16(BF[nt][1], AF[mt][1], acc[(MS)*4+mt][(NS)*2+nt]); \
        }                                                                          \
    } else {                                                                       \
      _Pragma("unroll")                                                            \
      for (int mt = 0; mt < 4; ++mt)                                               \
        _Pragma("unroll")                                                          \
        for (int nt = 0; nt < 2; ++nt) {                                           \
          acc[(MS)*4+mt][(NS)*2+nt] = MFMA16(AF[mt][0], BF[nt][0], acc[(MS)*4+mt][(NS)*2+nt]); \
          acc[(MS)*4+mt][(NS)*2+nt] = MFMA16(AF[mt][1], BF[nt][1], acc[(MS)*4+mt][(NS)*2+nt]); \
        }                                                                          \
    }                                                                              \
    __builtin_amdgcn_s_setprio(0);                                                 \
  } while (0)

__global__ __launch_bounds__(512, 2) void gemm_qkv(const unsigned short* __restrict__ A,
                                                   const unsigned short* __restrict__ B,
                                                   unsigned short* __restrict__ Qb,
                                                   unsigned short* __restrict__ Kb,
                                                   unsigned short* __restrict__ Vt)
{
  // shorts: buf b: A @ b*32768 (256 rows x 64), B @ b*32768+16384. 128 KiB.
  __shared__ unsigned short pool[65536];

  const int tid  = threadIdx.x;
  const int wave = tid >> 6, lane = tid & 63, quad = lane >> 4, cl = lane & 15;
  const int wm = wave >> 2, wn = wave & 3;

  // Bijective XCD chunking: 192 blocks, 24/XCD covering a 4(mb) x 6(nb) chunk.
  const int bid = blockIdx.x;
  const int xcd = bid & 7, j = bid >> 3;
  const int mb = (xcd >> 1) * 4 + j / 6;
  const int nb = (xcd & 1) * 6 + j % 6;
  const int m0 = mb * 256, n0 = nb * 256;
  const int part = nb >> 2;                 // 0=Q 1=K 2=V
  const bool swapped = (part < 2);

  // --- staging: per GLDS16, wave covers 8 rows x 128B linearly.
  // lane l -> row r0+(l>>3), phys slot l&7. Pre-swizzled global source:
  // logical slot = phys ^ (row&7) = (l&7) ^ (l>>3)   [r0 is a multiple of 8]
  const int lrow = lane >> 3;
  const int sg   = (lane & 7) ^ lrow;

  auto stageA = [&](int h0, int buf, int k0) {
    #pragma unroll
    for (int ii = 0; ii < 2; ++ii) {
      const int r0 = h0 + wave * 16 + ii * 8;
      GLDS16(A + (size_t)(m0 + r0 + lrow) * 1024 + k0 + sg * 8,
             &pool[buf * 32768 + r0 * 64]);
    }
  };
  auto stageB = [&](int h0, int buf, int k0) {
    #pragma unroll
    for (int ii = 0; ii < 2; ++ii) {
      const int r0 = h0 + wave * 16 + ii * 8;
      GLDS16(B + (size_t)(n0 + r0 + lrow) * 1024 + k0 + sg * 8,
             &pool[buf * 32768 + 16384 + r0 * 64]);
    }
  };

  // --- fragment reads: row = 16-aligned base + cl -> row&7 == cl&7.
  // logical k-chunk (kk*4+quad) lives at phys slot (kk*4+quad) ^ (cl&7).
  const int rswz = cl & 7;
  auto loadA = [&](bf16x8 (&af)[4][2], int msub, int b) {
    const unsigned short* base = &pool[b * 32768];
    #pragma unroll
    for (int mt = 0; mt < 4; ++mt) {
      const int row = wm * 128 + msub * 64 + mt * 16 + cl;
      #pragma unroll
      for (int kk = 0; kk < 2; ++kk)
        af[mt][kk] = *(const bf16x8*)&base[row * 64 + ((kk * 4 + quad) ^ rswz) * 8];
    }
  };
  auto loadB = [&](bf16x8 (&bf)[2][2], int nsub, int b) {
    const unsigned short* base = &pool[b * 32768 + 16384];
    #pragma unroll
    for (int nt = 0; nt < 2; ++nt) {
      const int row = wn * 64 + nsub * 32 + nt * 16 + cl;
      #pragma unroll
      for (int kk = 0; kk < 2; ++kk)
        bf[nt][kk] = *(const bf16x8*)&base[row * 64 + ((kk * 4 + quad) ^ rswz) * 8];
    }
  };

  f32x4 acc[8][4];
  #pragma unroll
  for (int i = 0; i < 8; ++i)
    #pragma unroll
    for (int jj = 0; jj < 4; ++jj)
      #pragma unroll
      for (int r = 0; r < 4; ++r) acc[i][jj][r] = 0.f;

  // Prologue: all 4 half-tiles of tile0, then lo halves of tile1 (12 loads).
  stageB(0,   0, 0);
  stageA(0,   0, 0);
  stageB(128, 0, 0);
  stageA(128, 0, 0);
  stageB(0,   1, 64);
  stageA(0,   1, 64);

  // vmcnt queue invariant (4 loads per stage-pair): entering tile t's wait,
  // outstanding = {t-lo(4), t-hi(4), t+1-lo(4)}; vmcnt(4) drains t-lo+t-hi
  // -> TILE t FULLY RESIDENT; {t+1-lo} stays in flight (never drained
  // in-loop). Stages below re-establish the invariant for t+1.
  #pragma unroll 1
  for (int t = 0; t < 16; ++t) {
    const int b = t & 1, bn = b ^ 1;
    const int kc  = (t + 1) * 64;
    const int kc2 = (t + 2) * 64;

    bf16x8 af0[4][2], af1[4][2], bfA[2][2], bfB[2][2];

    if (t < 15) { ASYNC_BAR(4); } else { ASYNC_BAR(0); }
    // Tile t fully resident: issue ALL 24 fragment reads now; their latency
    // drains under the q0/q1 MFMA clusters.
    loadA(af0, 0, b);
    loadB(bfA, 0, b);
    loadB(bfB, 1, b);
    loadA(af1, 1, b);
    if (t < 15) { stageB(128, bn, kc); stageA(128, bn, kc); }   // t+1 hi
    MMAC(af0, bfA, 0, 0);
    MMAC(af0, bfB, 0, 1);
    // All reads of buffer b are complete (lgkmcnt(0)) before any wave's
    // t+2-lo GLDS overwrites b's lo halves after the barrier.
    LGKM0();
    BAR();
    if (t < 14) { stageB(0, b, kc2); stageA(0, b, kc2); }       // t+2 lo
    MMAC(af1, bfB, 1, 1);
    MMAC(af1, bfA, 1, 0);
  }
  // ASYNC_BAR(0) at t=15 drained all staging: no GLDS in flight here.

  const int bb = m0 >> 11, ss = m0 & 2047;
  if (part < 2) {
    // Q/K (swapped: D=C^T): lane holds 4 consecutive d for one s -> ushort4
    unsigned short* dst = (part == 0) ? Qb : Kb;
    const float sc2 = (part == 0) ? LOG2E : 1.0f;
    const int npb = (n0 & 1023) + wn * 64;
    #pragma unroll
    for (int mt = 0; mt < 8; ++mt) {
      const int m = ss + wm * 128 + mt * 16 + cl;
      #pragma unroll
      for (int nt = 0; nt < 4; ++nt) {
        const int np = npb + nt * 16 + quad * 4;
        const int hh = np >> 6, d0 = np & 63;
        ushort4 pk;
        pk.x = f2bf(acc[mt][nt][0] * sc2);
        pk.y = f2bf(acc[mt][nt][1] * sc2);
        pk.z = f2bf(acc[mt][nt][2] * sc2);
        pk.w = f2bf(acc[mt][nt][3] * sc2);
        *(ushort4*)&dst[((size_t)(bb * 16 + hh) * 2048 + m) * 64 + d0] = pk;
      }
    }
  } else {
    // V (normal orientation): transpose through LDS (reuse pool),
    // trans[128][264] shorts per round; 2 rounds (wn pairs).
    unsigned short* trans = pool;
    #pragma unroll 1
    for (int r = 0; r < 2; ++r) {
      __syncthreads();
      if ((wn >> 1) == r) {
        #pragma unroll
        for (int mt = 0; mt < 8; ++mt) {
          const int s_l = wm * 128 + mt * 16 + quad * 4;
          #pragma unroll
          for (int nt = 0; nt < 4; ++nt) {
            const int n_l = (wn & 1) * 64 + nt * 16 + cl;
            ushort4 pk;
            pk.x = f2bf(acc[mt][nt][0]); pk.y = f2bf(acc[mt][nt][1]);
            pk.z = f2bf(acc[mt][nt][2]); pk.w = f2bf(acc[mt][nt][3]);
            *(ushort4*)&trans[n_l * 264 + s_l] = pk;
          }
        }
      }
      __syncthreads();
      const int row = tid >> 2, q4 = tid & 3;
      const int nv = (n0 & 1023) + r * 128 + row;
      const int hh = nv >> 6, d = nv & 63;
      unsigned short* drow = Vt + ((size_t)(bb * 16 + hh) * 64 + d) * 2048 + ss + q4 * 64;
      #pragma unroll
      for (int i = 0; i < 8; ++i)
        *(bf16x8*)(drow + i * 8) = *(const bf16x8*)&trans[row * 264 + q4 * 64 + i * 8];
    }
  }
}

// ---------------------------------------------------------------------------
// Out-projection (proven 128^2 structure): 4 waves, TRIPLE-buffered K-loop,
// counted vmcnt(4), grid 8x32 = 256 blocks.
// ---------------------------------------------------------------------------
__global__ __launch_bounds__(256) void gemm_obt(const unsigned short* __restrict__ A,
                                                const unsigned short* __restrict__ B,
                                                const float* __restrict__ bias,
                                                float* __restrict__ OutF)
{
  __shared__ unsigned short pool[24576];   // 3 stages x (A 4096 | B 4096) shorts

  const int tid  = threadIdx.x;
  const int wave = tid >> 6, lane = tid & 63, quad = lane >> 4, cl = lane & 15;
  const int wm = wave >> 1, wn = wave & 1;
  const int m0 = blockIdx.y * 128, n0 = blockIdx.x * 128;
  const int sr = lane >> 2, sc = lane & 3;

  f32x4 acc[4][4];
  #pragma unroll
  for (int i = 0; i < 4; ++i)
    #pragma unroll
    for (int j = 0; j < 4; ++j)
      #pragma unroll
      for (int r = 0; r < 4; ++r) acc[i][j][r] = 0.f;

  const int scs = (sc ^ ((sr >> 1) & 3)) * 8;
  const int rchunk = (quad ^ ((cl >> 1) & 3)) * 8;

  auto stage = [&](int k0, int buf) {
    unsigned short* As = pool + buf * 8192;
    unsigned short* Bs = As + 4096;
    #pragma unroll
    for (int ii = 0; ii < 2; ++ii) {
      const int r = wave * 32 + ii * 16 + sr;
      GLDS16(A + (size_t)(m0 + r) * 1024 + k0 + scs, &As[(wave * 32 + ii * 16) * 32]);
      GLDS16(B + (size_t)(n0 + r) * 1024 + k0 + scs, &Bs[(wave * 32 + ii * 16) * 32]);
    }
  };

  stage(0, 0);
  stage(32, 1);
  int cur = 0;
  #pragma unroll 1
  for (int it = 0; it < 32; ++it) {
    if (it + 2 < 32) {
      ASYNC_BAR(4);                              // drain stage(it); keep stage(it+1)
      const int bnx = (cur == 0) ? 2 : cur - 1;  // (cur+2)%3
      stage((it + 2) * 32, bnx);
    } else if (it + 1 < 32) {
      ASYNC_BAR(4);
    } else {
      ASYNC_BAR(0);
    }

    const unsigned short* As = pool + cur * 8192;
    const unsigned short* Bs = As + 4096;
    bf16x8 af[4], bfr[4];
    #pragma unroll
    for (int mt = 0; mt < 4; ++mt)
      af[mt] = *(const bf16x8*)&As[(wm * 64 + mt * 16 + cl) * 32 + rchunk];
    #pragma unroll
    for (int nt = 0; nt < 4; ++nt)
      bfr[nt] = *(const bf16x8*)&Bs[(wn * 64 + nt * 16 + cl) * 32 + rchunk];

    __builtin_amdgcn_s_setprio(1);
    #pragma unroll
    for (int mt = 0; mt < 4; ++mt)
      #pragma unroll
      for (int nt = 0; nt < 4; ++nt)
        acc[mt][nt] = MFMA16(bfr[nt], af[mt], acc[mt][nt]);   // D = C^T
    __builtin_amdgcn_s_setprio(0);
    cur = (cur == 2) ? 0 : cur + 1;
  }

  #pragma unroll
  for (int mt = 0; mt < 4; ++mt) {
    const int m = m0 + wm * 64 + mt * 16 + cl;
    #pragma unroll
    for (int nt = 0; nt < 4; ++nt) {
      const int n = n0 + wn * 64 + nt * 16 + quad * 4;
      const float4 bv = *(const float4*)(bias + n);
      float4 o;
      o.x = acc[mt][nt][0] + bv.x; o.y = acc[mt][nt][1] + bv.y;
      o.z = acc[mt][nt][2] + bv.z; o.w = acc[mt][nt][3] + bv.w;
      *(float4*)&OutF[(size_t)m * 1024 + n] = o;
    }
  }
}

// ---------------------------------------------------------------------------
// Flash attention (unchanged R22): 8-wave blocks (512 thr), 4 groups
// (G=4p'+g, uniform nch = p'+1), 2-way j-split: wave (g = w&3, s = w>>2)
// computes chunks 2t+s. KVBLK=128 rounds, shared dbuf staging, ONE
// vmcnt(0)+barrier per round. P-in-registers K=16 PV. End: s=1 partials ->
// LDS scratch (aliased over Ksm), s=0 adds + normalizes + writes CTX.
// LDS: Ksm 32KB + Vsm 32KB = 65536B -> 2 blocks/CU (16 waves/CU).
// ---------------------------------------------------------------------------
__global__ __launch_bounds__(512) void attn_mfma(const unsigned short* __restrict__ Qb,
                                                 const unsigned short* __restrict__ Kb,
                                                 const unsigned short* __restrict__ Vt,
                                                 unsigned short* __restrict__ CTX)
{
  __shared__ unsigned short Ksm[2][2][64 * 64];   // [round buf][sub][64 rows x 128B]
  __shared__ unsigned short Vsm[2][2][64 * 64];

  const int tid  = threadIdx.x;
  const int wave = tid >> 6, lane = tid & 63, quad = lane >> 4, cl = lane & 15;
  const int g = wave & 3, sp = wave >> 2;         // group-slot, j-split index

  const int L  = blockIdx.x;
  const int bh = 4 * (L & 7) + ((L >> 3) & 3);    // XCD-affine: 4 bh per XCD
  const int b  = bh >> 4, h = bh & 15;
  const int pp = 31 - (L >> 5);                   // 0..31, big-work-first
  const int G  = pp * 4 + g;                      // q-group 0..127
  const int qb = G * 16;
  const size_t base = (size_t)bh * (2048 * 64);

  bf16x8 qf[2];
  #pragma unroll
  for (int dk = 0; dk < 2; ++dk)
    qf[dk] = *(const bf16x8*)(Qb + base + (size_t)(qb + cl) * 64 + dk * 32 + quad * 8);

  f32x4 oacc[4];
  #pragma unroll
  for (int dt = 0; dt < 4; ++dt)
    #pragma unroll
    for (int r = 0; r < 4; ++r) oacc[dt][r] = 0.f;
  float lr[4] = {};

  bf16x4 ones4;
  #pragma unroll
  for (int k = 0; k < 4; ++k) ones4[k] = (short)0x3F80;

  const int lrow  = lane >> 3;
  const int lslot = (lane & 7) ^ lrow;
  const int nch = pp + 1;                          // 64-chunks: 1..32
  const int nrd = (nch + 1) >> 1;                  // 128-rounds: 1..16

  // Stage one 64-j sub-chunk, 8 waves x 8 rows each (row = wave*8 + lrow).
  auto stageKV = [&](int ch, int buf, int sub) {
    const int j64 = ch * 64;
    const int r0 = wave * 8;
    GLDS16(Kb + base + (size_t)(j64 + r0 + lrow) * 64 + lslot * 8,
           &Ksm[buf][sub][r0 * 64]);
    GLDS16(Vt + base + (size_t)(r0 + lrow) * 2048 + j64 + lslot * 8,
           &Vsm[buf][sub][r0 * 64]);
  };

  // Prologue: round 0 = chunks 0,1 (chunk 1 always within the 2048-row
  // arrays; if unused (pp=0) it is drained by the round-0 ASYNC_BAR(0)).
  stageKV(0, 0, 0);
  stageKV(1, 0, 1);

  #pragma unroll 1
  for (int t = 0; t < nrd; ++t) {
    // Drain round t's 4 GLDS (issued a full round ago; K/V L2-resident) and
    // sync. Barrier also proves all waves are past round t-1's reads of
    // buf[(t+1)&1] -> safe to overwrite.
    ASYNC_BAR(0);
    if (t + 1 < nrd) {
      stageKV(2 * t + 2, (t + 1) & 1, 0);
      stageKV(2 * t + 3, (t + 1) & 1, 1);
    }

    // This wave computes ONLY chunk 2t+sp for its group.
    {
      const int ch = 2 * t + sp;
      const unsigned short* Kc = Ksm[t & 1][sp];
      const unsigned short* Vc = Vsm[t & 1][sp];
      const int j64c = ch * 64;

      #pragma unroll
      for (int jli = 0; jli < 2; ++jli) {
        const int jg0 = j64c + jli * 32;
        if (jg0 > qb + 15) continue;               // causal skip (covers ch>=nch too)
        const int jl = jli * 32;

        bf16x8 kf[2][2];
        #pragma unroll
        for (int jf = 0; jf < 2; ++jf)
          #pragma unroll
          for (int dk = 0; dk < 2; ++dk) {
            const int jrow = jl + jf * 16 + cl;
            const int slot = (dk * 4 + quad) ^ (cl & 7);
            kf[jf][dk] = *(const bf16x8*)&Kc[jrow * 64 + slot * 8];
          }

        f32x4 st[2];
        __builtin_amdgcn_s_setprio(1);
        #pragma unroll
        for (int jf = 0; jf < 2; ++jf) {
          f32x4 z;
          #pragma unroll
          for (int r = 0; r < 4; ++r) z[r] = 0.f;
          z = MFMA16(kf[jf][0], qf[0], z);
          st[jf] = MFMA16(kf[jf][1], qf[1], z);
        }
        __builtin_amdgcn_s_setprio(0);

        // softmax: P[q=cl][jf*16+quad*4+r] packed to bf16 IN REGISTERS.
        // w[jf] (2 u32 = 4 bf16) is exactly the 16x16x16 A-fragment
        // A[m=cl][k=quad*4+i] for the j-16-block (jl+jf*16).
        const bool diag = (jg0 + 32 > qb);
        uint2 w[2];
        #pragma unroll
        for (int jf = 0; jf < 2; ++jf) {
          float pv[4];
          if (diag) {
            const int qg = qb + cl;
            #pragma unroll
            for (int r = 0; r < 4; ++r) {
              const int jg = jg0 + jf * 16 + quad * 4 + r;
              pv[r] = (jg <= qg) ? EXP2F(st[jf][r]) : 0.f;
            }
          } else {
            #pragma unroll
            for (int r = 0; r < 4; ++r) pv[r] = EXP2F(st[jf][r]);
          }
          w[jf].x = pk2bf(pv[0], pv[1]);
          w[jf].y = pk2bf(pv[2], pv[3]);
        }
        const bf16x4 pf0 = __builtin_bit_cast(bf16x4, w[0]);
        const bf16x4 pf1 = __builtin_bit_cast(bf16x4, w[1]);

        // V fragments for 16x16x16 B[n=d][k=quad*4+i]: j = jl+jf*16+quad*4+i.
        // logical 16B slot = (jl>>3)+jf*2+(quad>>1), 8B half = quad&1;
        // phys slot = logical ^ (d&7) = logical ^ (cl&7)  [same involution].
        bf16x4 vf[2][4];
        #pragma unroll
        for (int jf = 0; jf < 2; ++jf) {
          const int slog = (jl >> 3) + jf * 2 + (quad >> 1);
          const int soff = ((slog ^ (cl & 7)) << 3) + ((quad & 1) << 2);
          #pragma unroll
          for (int dt = 0; dt < 4; ++dt) {
            const int d = dt * 16 + cl;
            vf[jf][dt] = *(const bf16x4*)&Vc[d * 64 + soff];
          }
        }

        __builtin_amdgcn_s_setprio(1);
        {
          f32x4 ls;
          #pragma unroll
          for (int r = 0; r < 4; ++r) ls[r] = 0.f;
          ls = MFMAK16(pf0, ones4, ls);
          ls = MFMAK16(pf1, ones4, ls);
          #pragma unroll
          for (int r = 0; r < 4; ++r) lr[r] += ls[r];
          #pragma unroll
          for (int dt = 0; dt < 4; ++dt) {
            oacc[dt] = MFMAK16(pf0, vf[0][dt], oacc[dt]);
            oacc[dt] = MFMAK16(pf1, vf[1][dt], oacc[dt]);
          }
        }
        __builtin_amdgcn_s_setprio(0);
      }
    }
  }

  // --- cross-split reduction: O = O_s0 + O_s1, l = l_s0 + l_s1 (exact:
  // no-max softmax partials are pure sums). Scratch aliases Ksm; the
  // barrier below orders it after the last K/V reads.
  __syncthreads();
  float* scr = reinterpret_cast<float*>(&Ksm[0][0][0]);   // 4*64*20*4B = 20KB
  const int si = (g * 64 + lane) * 20;
  if (sp == 1) {
    #pragma unroll
    for (int dt = 0; dt < 4; ++dt)
      *(f32x4*)&scr[si + dt * 4] = oacc[dt];
    #pragma unroll
    for (int r = 0; r < 4; ++r) scr[si + 16 + r] = lr[r];
  }
  __syncthreads();
  if (sp == 0) {
    #pragma unroll
    for (int dt = 0; dt < 4; ++dt) {
      const f32x4 o2 = *(const f32x4*)&scr[si + dt * 4];
      #pragma unroll
      for (int r = 0; r < 4; ++r) oacc[dt][r] += o2[r];
    }
    float inv[4];
    #pragma unroll
    for (int r = 0; r < 4; ++r) inv[r] = 1.f / (lr[r] + scr[si + 16 + r]);
    #pragma unroll
    for (int dt = 0; dt < 4; ++dt)
      #pragma unroll
      for (int r = 0; r < 4; ++r)
        CTX[(size_t)(b * 2048 + qb + quad * 4 + r) * 1024 +
            h * 64 + dt * 16 + cl] = f2bf(oacc[dt][r] * inv[r]);
  }
}

// ---------------------------------------------------------------------------
extern "C" void kernel_launch(void* const* d_in, const int* in_sizes, int n_in,
                              void* d_out, int out_size, void* d_ws, size_t ws_size,
                              hipStream_t stream)
{
  const float* x    = (const float*)d_in[0];
  const float* Wqkv = (const float*)d_in[1];
  const float* Wout = (const float*)d_in[2];
  const float* bout = (const float*)d_in[3];
  float* out = (float*)d_out;

  char* ws = (char*)d_ws;
  unsigned short* xb  = (unsigned short*)(ws);
  unsigned short* wqb = (unsigned short*)(ws + 8388608);
  unsigned short* wob = (unsigned short*)(ws + 14680064);
  unsigned short* Qb  = (unsigned short*)(ws + 16777216);
  unsigned short* Kb  = (unsigned short*)(ws + 25165824);
  unsigned short* Vt  = (unsigned short*)(ws + 33554432);
  unsigned short* CTX = (unsigned short*)(ws + 41943040);

  cast_bf16<<<dim3(8192), dim3(256), 0, stream>>>(x, Wqkv, Wout, xb, wqb, wob);

  // QKV projection: M=4096, N=3072, K=1024 -- 256^2 tile, 192 blocks
  gemm_qkv<<<dim3(192), dim3(512), 0, stream>>>(xb, wqb, Qb, Kb, Vt);

  // Flash attention: 1024 blocks (32 bh x 32 p'), 8 waves, 2-way j-split
  attn_mfma<<<dim3(1024), dim3(512), 0, stream>>>(Qb, Kb, Vt, CTX);

  // Output projection: M=4096, N=1024, K=1024, + bias (proven 128^2 kernel)
  gemm_obt<<<dim3(8, 32), dim3(256), 0, stream>>>(CTX, wob, bout, out);
}

// Round 14
// 183.223 us; speedup vs baseline: 1.1817x; 1.1817x over previous
//
#include <hip/hip_runtime.h>
#include <cstdint>
#include <cstddef>

// MultiHeadAttention R24:
//   gemm_qkv REVERTED to R22 (R23's 24-live-fragment hoist spilled to
//   scratch: WRITE_SIZE 24.6->40.4MB, qkv 55->87us. Lesson: per-phase
//   register working set must stay at one quadrant).
//   gemm_obt, cast unchanged.
//   attn_mfma: j-split widened 2-way -> 4-WAY (the only attn lever that
//   worked; R22 -9.25us). 1024-thr blocks (16 waves), wave (g=w&3,
//   sp=w>>2), sp computes chunks 4t+sp; rounds cover 256 j, nrd<=8 (was
//   16). Staging: waves 0-7 stage K's 4 sub-chunks, waves 8-15 stage V
//   (4 GLDS/wave/round, same rows/swizzle, one vmcnt(0)+barrier per
//   round). LDS 128KB -> 1 block/CU = 16 waves/CU (same as R22).
//   Reduction: sp>0 partials -> scratch aliased over Ksm (61.4KB, after
//   full barrier), sp=0 sums + normalizes. Causal skip covers ch>pp
//   (sp>0 waves contribute exact zeros in the pp=0 corner).
// ws layout (bytes):
//   xb @0 [4096][1024] bf16 | wqb @8388608 [3072][1024] | wob @14680064 [1024][1024]
//   Qb @16777216, Kb @25165824: [2][16][2048][64] bf16 (Qb = Q*log2e)
//   Vt @33554432: [2][16][64][2048] bf16 (transposed)
//   CTX @41943040 [4096][1024] bf16
// MFMA 16x16x32_bf16 frags: A[m=lane&15][k=quad*8+i], B[n=lane&15][k=quad*8+i],
// C/D[row=quad*4+reg][col=lane&15]. 16x16x16: k=quad*4+i, same C/D.
// Swapped operands -> D = C^T.

typedef __attribute__((ext_vector_type(8))) short bf16x8;
typedef __attribute__((ext_vector_type(4))) short bf16x4;
typedef __attribute__((ext_vector_type(4))) float f32x4;

#define LOG2E 1.44269504f

#define MFMA16(a, b, c) __builtin_amdgcn_mfma_f32_16x16x32_bf16((a), (b), (c), 0, 0, 0)

// K=16 bf16 MFMA: guard must only run in the DEVICE pass -- __has_builtin
// returns false for amdgcn builtins during hipcc's host pass (R10 lesson).
#if defined(__HIP_DEVICE_COMPILE__)
  #if __has_builtin(__builtin_amdgcn_mfma_f32_16x16x16bf16_1k)
    #define MFMAK16(a, b, c) __builtin_amdgcn_mfma_f32_16x16x16bf16_1k((a), (b), (c), 0, 0, 0)
  #elif __has_builtin(__builtin_amdgcn_mfma_f32_16x16x16_bf16)
    #define MFMAK16(a, b, c) __builtin_amdgcn_mfma_f32_16x16x16_bf16((a), (b), (c), 0, 0, 0)
  #else
    #error "no 16x16x16 bf16 MFMA builtin on device"
  #endif
#else
  #define MFMAK16(a, b, c) (c)   // host pass: parsed, never executed
#endif

#define GLDS16(g, s)                                                        \
  __builtin_amdgcn_global_load_lds(                                         \
      (const __attribute__((address_space(1))) void*)(g),                   \
      (__attribute__((address_space(3))) void*)(s), 16, 0, 0)

// Manual barrier: wait until <= N vector-memory ops outstanding, then barrier.
// ONLY valid when the loop's vmem traffic is exclusively the staged GLDS.
#define ASYNC_BAR(N) asm volatile("s_waitcnt vmcnt(" #N ")\n\ts_barrier" ::: "memory")
#define BAR() asm volatile("s_barrier" ::: "memory")

// Native 2^x: v_exp_f32 (gfx950 VOP1). Input already in log2 domain.
static __device__ __forceinline__ float exp2_hw(float x) {
  float r;
  asm("v_exp_f32 %0, %1" : "=v"(r) : "v"(x));
  return r;
}
#define EXP2F(x) exp2_hw(x)

static __device__ __forceinline__ unsigned short f2bf(float f) {  // RNE
  unsigned int u = __builtin_bit_cast(unsigned int, f);
  u += 0x7FFFu + ((u >> 16) & 1u);
  return (unsigned short)(u >> 16);
}

// pack two fp32 -> two bf16 (round-nearest) in one u32: 2 add + 1 perm
static __device__ __forceinline__ unsigned int pk2bf(float a, float b) {
  const unsigned int ua = __builtin_bit_cast(unsigned int, a) + 0x8000u;
  const unsigned int ub = __builtin_bit_cast(unsigned int, b) + 0x8000u;
  return __builtin_amdgcn_perm(ub, ua, 0x07060302);
}

// ---------------------------------------------------------------------------
__global__ __launch_bounds__(256) void cast_bf16(const float* __restrict__ x,
                                                 const float* __restrict__ wq,
                                                 const float* __restrict__ wo,
                                                 unsigned short* __restrict__ xb,
                                                 unsigned short* __restrict__ wqb,
                                                 unsigned short* __restrict__ wob)
{
  const int id = blockIdx.x * 256 + threadIdx.x;
  const float* src;
  unsigned short* dst;
  int off;
  if (id < 1048576)               { src = x;  dst = xb;  off = id; }
  else if (id < 1048576 + 786432) { src = wq; dst = wqb; off = id - 1048576; }
  else                            { src = wo; dst = wob; off = id - (1048576 + 786432); }
  float4 v = ((const float4*)src)[off];
  ushort4 o;
  o.x = f2bf(v.x); o.y = f2bf(v.y); o.z = f2bf(v.z); o.w = f2bf(v.w);
  ((ushort4*)dst)[off] = o;
}

// ---------------------------------------------------------------------------
// QKV GEMM (R22 version, reverted from R23): 256x256 tile, BK=64, 512
// threads = 8 waves (2M x 4N), per-wave 128x64 output (acc[8][4]).
// LDS 128 KiB: 2 buffers x (A 256x64 | B 256x64) bf16, rows of 128B split
// into 8x16B slots, phys_slot = logical_slot ^ (row & 7)   [FULL 3-bit XOR].
// 4 phases per K-tile, 16 MFMA each; ONE vmcnt(4) per K-tile.
// ---------------------------------------------------------------------------
#define MMAC(AF, BF, MS, NS)                                                       \
  do {                                                                             \
    __builtin_amdgcn_s_setprio(1);                                                 \
    if (swapped) {                                                                 \
      _Pragma("unroll")                                                            \
      for (int mt = 0; mt < 4; ++mt)                                               \
        _Pragma("unroll")                                                          \
        for (int nt = 0; nt < 2; ++nt) {                                           \
          acc[(MS)*4+mt][(NS)*2+nt] = MFMA16(BF[nt][0], AF[mt][0], acc[(MS)*4+mt][(NS)*2+nt]); \
          acc[(MS)*4+mt][(NS)*2+nt] = MFMA16(BF[nt][1], AF[mt][1], acc[(MS)*4+mt][(NS)*2+nt]); \
        }                                                                          \
    } else {                                                                       \
      _Pragma("unroll")                                                            \
      for (int mt = 0; mt < 4; ++mt)                                               \
        _Pragma("unroll")                                                          \
        for (int nt = 0; nt < 2; ++nt) {                                           \
          acc[(MS)*4+mt][(NS)*2+nt] = MFMA16(AF[mt][0], BF[nt][0], acc[(MS)*4+mt][(NS)*2+nt]); \
          acc[(MS)*4+mt][(NS)*2+nt] = MFMA16(AF[mt][1], BF[nt][1], acc[(MS)*4+mt][(NS)*2+nt]); \
        }                                                                          \
    }                                                                              \
    __builtin_amdgcn_s_setprio(0);                                                 \
  } while (0)

__global__ __launch_bounds__(512, 2) void gemm_qkv(const unsigned short* __restrict__ A,
                                                   const unsigned short* __restrict__ B,
                                                   unsigned short* __restrict__ Qb,
                                                   unsigned short* __restrict__ Kb,
                                                   unsigned short* __restrict__ Vt)
{
  // shorts: buf b: A @ b*32768 (256 rows x 64), B @ b*32768+16384. 128 KiB.
  __shared__ unsigned short pool[65536];

  const int tid  = threadIdx.x;
  const int wave = tid >> 6, lane = tid & 63, quad = lane >> 4, cl = lane & 15;
  const int wm = wave >> 2, wn = wave & 3;

  // Bijective XCD chunking: 192 blocks, 24/XCD covering a 4(mb) x 6(nb) chunk.
  const int bid = blockIdx.x;
  const int xcd = bid & 7, j = bid >> 3;
  const int mb = (xcd >> 1) * 4 + j / 6;
  const int nb = (xcd & 1) * 6 + j % 6;
  const int m0 = mb * 256, n0 = nb * 256;
  const int part = nb >> 2;                 // 0=Q 1=K 2=V
  const bool swapped = (part < 2);

  // --- staging: per GLDS16, wave covers 8 rows x 128B linearly.
  // lane l -> row r0+(l>>3), phys slot l&7. Pre-swizzled global source:
  // logical slot = phys ^ (row&7) = (l&7) ^ (l>>3)   [r0 is a multiple of 8]
  const int lrow = lane >> 3;
  const int sg   = (lane & 7) ^ lrow;

  auto stageA = [&](int h0, int buf, int k0) {
    #pragma unroll
    for (int ii = 0; ii < 2; ++ii) {
      const int r0 = h0 + wave * 16 + ii * 8;
      GLDS16(A + (size_t)(m0 + r0 + lrow) * 1024 + k0 + sg * 8,
             &pool[buf * 32768 + r0 * 64]);
    }
  };
  auto stageB = [&](int h0, int buf, int k0) {
    #pragma unroll
    for (int ii = 0; ii < 2; ++ii) {
      const int r0 = h0 + wave * 16 + ii * 8;
      GLDS16(B + (size_t)(n0 + r0 + lrow) * 1024 + k0 + sg * 8,
             &pool[buf * 32768 + 16384 + r0 * 64]);
    }
  };

  // --- fragment reads: row = 16-aligned base + cl -> row&7 == cl&7.
  // logical k-chunk (kk*4+quad) lives at phys slot (kk*4+quad) ^ (cl&7).
  const int rswz = cl & 7;
  auto loadA = [&](bf16x8 (&af)[4][2], int msub, int b) {
    const unsigned short* base = &pool[b * 32768];
    #pragma unroll
    for (int mt = 0; mt < 4; ++mt) {
      const int row = wm * 128 + msub * 64 + mt * 16 + cl;
      #pragma unroll
      for (int kk = 0; kk < 2; ++kk)
        af[mt][kk] = *(const bf16x8*)&base[row * 64 + ((kk * 4 + quad) ^ rswz) * 8];
    }
  };
  auto loadB = [&](bf16x8 (&bf)[2][2], int nsub, int b) {
    const unsigned short* base = &pool[b * 32768 + 16384];
    #pragma unroll
    for (int nt = 0; nt < 2; ++nt) {
      const int row = wn * 64 + nsub * 32 + nt * 16 + cl;
      #pragma unroll
      for (int kk = 0; kk < 2; ++kk)
        bf[nt][kk] = *(const bf16x8*)&base[row * 64 + ((kk * 4 + quad) ^ rswz) * 8];
    }
  };

  f32x4 acc[8][4];
  #pragma unroll
  for (int i = 0; i < 8; ++i)
    #pragma unroll
    for (int jj = 0; jj < 4; ++jj)
      #pragma unroll
      for (int r = 0; r < 4; ++r) acc[i][jj][r] = 0.f;

  // Prologue: all 4 half-tiles of tile0, then lo halves of tile1 (12 loads).
  stageB(0,   0, 0);
  stageA(0,   0, 0);
  stageB(128, 0, 0);
  stageA(128, 0, 0);
  stageB(0,   1, 64);
  stageA(0,   1, 64);

  #pragma unroll 1
  for (int t = 0; t < 16; ++t) {
    const int b = t & 1, bn = b ^ 1;
    const int kc  = (t + 1) * 64;
    const int kc2 = (t + 2) * 64;

    bf16x8 af[4][2], bfA[2][2], bfB[2][2];

    // P0: quadrant (0,0). vmcnt(4): guarantees all 4 halves of tile t
    // (newest needed = A-hi(t) @ (t-1)-P1; newer in flight = B-lo/A-lo(t+1)).
    if (t < 15) { ASYNC_BAR(4); } else { ASYNC_BAR(0); }
    loadA(af, 0, b);
    loadB(bfA, 0, b);
    if (t < 15) stageB(128, bn, kc);       // B-hi(t+1)
    MMAC(af, bfA, 0, 0);

    // P1: quadrant (0,1). No barrier needed: reads tile-t B (published at P0),
    // GLDS writes buffer bn (not being read).
    loadB(bfB, 1, b);
    if (t < 15) stageA(128, bn, kc);       // A-hi(t+1)
    MMAC(af, bfB, 0, 1);

    // P2: quadrant (1,1). Barrier: B-lo(t+2) overwrites B-lo(b) whose last
    // reads were P1 (other waves).
    BAR();
    loadA(af, 1, b);
    if (t < 14) stageB(0, b, kc2);         // B-lo(t+2)
    MMAC(af, bfB, 1, 1);

    // P3: quadrant (1,0), reuses bfA regs. Barrier: A-lo(t+2) overwrites
    // A-lo(b) whose last reads were P2 (wm=0 waves).
    BAR();
    if (t < 14) stageA(0, b, kc2);         // A-lo(t+2)
    MMAC(af, bfA, 1, 0);
  }
  // ASYNC_BAR(0) at t=15-P0 drained all staging: no GLDS in flight here.

  const int bb = m0 >> 11, ss = m0 & 2047;
  if (part < 2) {
    // Q/K (swapped: D=C^T): lane holds 4 consecutive d for one s -> ushort4
    unsigned short* dst = (part == 0) ? Qb : Kb;
    const float sc2 = (part == 0) ? LOG2E : 1.0f;
    const int npb = (n0 & 1023) + wn * 64;
    #pragma unroll
    for (int mt = 0; mt < 8; ++mt) {
      const int m = ss + wm * 128 + mt * 16 + cl;
      #pragma unroll
      for (int nt = 0; nt < 4; ++nt) {
        const int np = npb + nt * 16 + quad * 4;
        const int hh = np >> 6, d0 = np & 63;
        ushort4 pk;
        pk.x = f2bf(acc[mt][nt][0] * sc2);
        pk.y = f2bf(acc[mt][nt][1] * sc2);
        pk.z = f2bf(acc[mt][nt][2] * sc2);
        pk.w = f2bf(acc[mt][nt][3] * sc2);
        *(ushort4*)&dst[((size_t)(bb * 16 + hh) * 2048 + m) * 64 + d0] = pk;
      }
    }
  } else {
    // V (normal orientation): transpose through LDS (reuse pool),
    // trans[128][264] shorts per round; 2 rounds (wn pairs).
    unsigned short* trans = pool;
    #pragma unroll 1
    for (int r = 0; r < 2; ++r) {
      __syncthreads();
      if ((wn >> 1) == r) {
        #pragma unroll
        for (int mt = 0; mt < 8; ++mt) {
          const int s_l = wm * 128 + mt * 16 + quad * 4;
          #pragma unroll
          for (int nt = 0; nt < 4; ++nt) {
            const int n_l = (wn & 1) * 64 + nt * 16 + cl;
            ushort4 pk;
            pk.x = f2bf(acc[mt][nt][0]); pk.y = f2bf(acc[mt][nt][1]);
            pk.z = f2bf(acc[mt][nt][2]); pk.w = f2bf(acc[mt][nt][3]);
            *(ushort4*)&trans[n_l * 264 + s_l] = pk;
          }
        }
      }
      __syncthreads();
      const int row = tid >> 2, q4 = tid & 3;
      const int nv = (n0 & 1023) + r * 128 + row;
      const int hh = nv >> 6, d = nv & 63;
      unsigned short* drow = Vt + ((size_t)(bb * 16 + hh) * 64 + d) * 2048 + ss + q4 * 64;
      #pragma unroll
      for (int i = 0; i < 8; ++i)
        *(bf16x8*)(drow + i * 8) = *(const bf16x8*)&trans[row * 264 + q4 * 64 + i * 8];
    }
  }
}

// ---------------------------------------------------------------------------
// Out-projection (proven 128^2 structure): 4 waves, TRIPLE-buffered K-loop,
// counted vmcnt(4), grid 8x32 = 256 blocks.
// ---------------------------------------------------------------------------
__global__ __launch_bounds__(256) void gemm_obt(const unsigned short* __restrict__ A,
                                                const unsigned short* __restrict__ B,
                                                const float* __restrict__ bias,
                                                float* __restrict__ OutF)
{
  __shared__ unsigned short pool[24576];   // 3 stages x (A 4096 | B 4096) shorts

  const int tid  = threadIdx.x;
  const int wave = tid >> 6, lane = tid & 63, quad = lane >> 4, cl = lane & 15;
  const int wm = wave >> 1, wn = wave & 1;
  const int m0 = blockIdx.y * 128, n0 = blockIdx.x * 128;
  const int sr = lane >> 2, sc = lane & 3;

  f32x4 acc[4][4];
  #pragma unroll
  for (int i = 0; i < 4; ++i)
    #pragma unroll
    for (int j = 0; j < 4; ++j)
      #pragma unroll
      for (int r = 0; r < 4; ++r) acc[i][j][r] = 0.f;

  const int scs = (sc ^ ((sr >> 1) & 3)) * 8;
  const int rchunk = (quad ^ ((cl >> 1) & 3)) * 8;

  auto stage = [&](int k0, int buf) {
    unsigned short* As = pool + buf * 8192;
    unsigned short* Bs = As + 4096;
    #pragma unroll
    for (int ii = 0; ii < 2; ++ii) {
      const int r = wave * 32 + ii * 16 + sr;
      GLDS16(A + (size_t)(m0 + r) * 1024 + k0 + scs, &As[(wave * 32 + ii * 16) * 32]);
      GLDS16(B + (size_t)(n0 + r) * 1024 + k0 + scs, &Bs[(wave * 32 + ii * 16) * 32]);
    }
  };

  stage(0, 0);
  stage(32, 1);
  int cur = 0;
  #pragma unroll 1
  for (int it = 0; it < 32; ++it) {
    if (it + 2 < 32) {
      ASYNC_BAR(4);                              // drain stage(it); keep stage(it+1)
      const int bnx = (cur == 0) ? 2 : cur - 1;  // (cur+2)%3
      stage((it + 2) * 32, bnx);
    } else if (it + 1 < 32) {
      ASYNC_BAR(4);
    } else {
      ASYNC_BAR(0);
    }

    const unsigned short* As = pool + cur * 8192;
    const unsigned short* Bs = As + 4096;
    bf16x8 af[4], bfr[4];
    #pragma unroll
    for (int mt = 0; mt < 4; ++mt)
      af[mt] = *(const bf16x8*)&As[(wm * 64 + mt * 16 + cl) * 32 + rchunk];
    #pragma unroll
    for (int nt = 0; nt < 4; ++nt)
      bfr[nt] = *(const bf16x8*)&Bs[(wn * 64 + nt * 16 + cl) * 32 + rchunk];

    __builtin_amdgcn_s_setprio(1);
    #pragma unroll
    for (int mt = 0; mt < 4; ++mt)
      #pragma unroll
      for (int nt = 0; nt < 4; ++nt)
        acc[mt][nt] = MFMA16(bfr[nt], af[mt], acc[mt][nt]);   // D = C^T
    __builtin_amdgcn_s_setprio(0);
    cur = (cur == 2) ? 0 : cur + 1;
  }

  #pragma unroll
  for (int mt = 0; mt < 4; ++mt) {
    const int m = m0 + wm * 64 + mt * 16 + cl;
    #pragma unroll
    for (int nt = 0; nt < 4; ++nt) {
      const int n = n0 + wn * 64 + nt * 16 + quad * 4;
      const float4 bv = *(const float4*)(bias + n);
      float4 o;
      o.x = acc[mt][nt][0] + bv.x; o.y = acc[mt][nt][1] + bv.y;
      o.z = acc[mt][nt][2] + bv.z; o.w = acc[mt][nt][3] + bv.w;
      *(float4*)&OutF[(size_t)m * 1024 + n] = o;
    }
  }
}

// ---------------------------------------------------------------------------
// Flash attention R24: 16-wave blocks (1024 thr), 4 groups (G=4p'+g,
// uniform nch = p'+1), 4-WAY j-split: wave (g = w&3, sp = w>>2) computes
// chunks 4t+sp. Rounds cover 256 j; nrd = ceil(nch/4) <= 8. Staging:
// waves 0-7 stage K's 4 sub-chunks (rows (w&7)*8), waves 8-15 stage V;
// 4 GLDS/wave/round; ONE vmcnt(0)+barrier per round; dist-1 round dbuf.
// P-in-registers K=16 PV (R21). End: sp>0 partials -> LDS scratch (61.4KB
// aliased over Ksm, after full barrier), sp=0 sums 3 + normalizes.
// LDS: Ksm 64KB + Vsm 64KB = 131072B -> 1 block/CU (16 waves/CU).
// ---------------------------------------------------------------------------
__global__ __launch_bounds__(1024) void attn_mfma(const unsigned short* __restrict__ Qb,
                                                  const unsigned short* __restrict__ Kb,
                                                  const unsigned short* __restrict__ Vt,
                                                  unsigned short* __restrict__ CTX)
{
  __shared__ unsigned short Ksm[2][4][64 * 64];   // [round buf][sub][64 rows x 128B]
  __shared__ unsigned short Vsm[2][4][64 * 64];

  const int tid  = threadIdx.x;
  const int wave = tid >> 6, lane = tid & 63, quad = lane >> 4, cl = lane & 15;
  const int g = wave & 3, sp = wave >> 2;         // group-slot, j-split index 0..3

  const int L  = blockIdx.x;
  const int bh = 4 * (L & 7) + ((L >> 3) & 3);    // XCD-affine: 4 bh per XCD
  const int b  = bh >> 4, h = bh & 15;
  const int pp = 31 - (L >> 5);                   // 0..31, big-work-first
  const int G  = pp * 4 + g;                      // q-group 0..127
  const int qb = G * 16;
  const size_t base = (size_t)bh * (2048 * 64);

  bf16x8 qf[2];
  #pragma unroll
  for (int dk = 0; dk < 2; ++dk)
    qf[dk] = *(const bf16x8*)(Qb + base + (size_t)(qb + cl) * 64 + dk * 32 + quad * 8);

  f32x4 oacc[4];
  #pragma unroll
  for (int dt = 0; dt < 4; ++dt)
    #pragma unroll
    for (int r = 0; r < 4; ++r) oacc[dt][r] = 0.f;
  float lr[4] = {};

  bf16x4 ones4;
  #pragma unroll
  for (int k = 0; k < 4; ++k) ones4[k] = (short)0x3F80;

  const int lrow  = lane >> 3;
  const int lslot = (lane & 7) ^ lrow;
  const int nch = pp + 1;                          // 64-chunks: 1..32
  const int nrd = (nch + 3) >> 2;                  // 256-rounds: 1..8

  // Stage one round (4 sub-chunks): waves 0-7 cover K (rows (w&7)*8 of each
  // sub), waves 8-15 cover V. 4 GLDS per wave. Max staged chunk 4*7+3=31.
  auto stageRound = [&](int t, int buf) {
    const int r0 = (wave & 7) * 8;
    if (wave < 8) {
      #pragma unroll
      for (int s = 0; s < 4; ++s) {
        const int j64 = (4 * t + s) * 64;
        GLDS16(Kb + base + (size_t)(j64 + r0 + lrow) * 64 + lslot * 8,
               &Ksm[buf][s][r0 * 64]);
      }
    } else {
      #pragma unroll
      for (int s = 0; s < 4; ++s) {
        const int j64 = (4 * t + s) * 64;
        GLDS16(Vt + base + (size_t)(r0 + lrow) * 2048 + j64 + lslot * 8,
               &Vsm[buf][s][r0 * 64]);
      }
    }
  };

  // Prologue: round 0 = chunks 0..3 (all within the 2048-row arrays; any
  // unused for small pp are drained by the round-0 ASYNC_BAR(0)).
  stageRound(0, 0);

  #pragma unroll 1
  for (int t = 0; t < nrd; ++t) {
    // Drain round t's 4 GLDS (issued a full round ago; K/V L2-resident) and
    // sync. Barrier also proves all waves are past round t-1's reads of
    // buf[(t+1)&1] -> safe to overwrite.
    ASYNC_BAR(0);
    if (t + 1 < nrd) stageRound(t + 1, (t + 1) & 1);

    // This wave computes ONLY chunk 4t+sp for its group (causal skip
    // covers ch >= nch: 64*ch > qb+15 for all such waves).
    {
      const int ch = 4 * t + sp;
      const unsigned short* Kc = Ksm[t & 1][sp];
      const unsigned short* Vc = Vsm[t & 1][sp];
      const int j64c = ch * 64;

      #pragma unroll
      for (int jli = 0; jli < 2; ++jli) {
        const int jg0 = j64c + jli * 32;
        if (jg0 > qb + 15) continue;
        const int jl = jli * 32;

        bf16x8 kf[2][2];
        #pragma unroll
        for (int jf = 0; jf < 2; ++jf)
          #pragma unroll
          for (int dk = 0; dk < 2; ++dk) {
            const int jrow = jl + jf * 16 + cl;
            const int slot = (dk * 4 + quad) ^ (cl & 7);
            kf[jf][dk] = *(const bf16x8*)&Kc[jrow * 64 + slot * 8];
          }

        f32x4 st[2];
        __builtin_amdgcn_s_setprio(1);
        #pragma unroll
        for (int jf = 0; jf < 2; ++jf) {
          f32x4 z;
          #pragma unroll
          for (int r = 0; r < 4; ++r) z[r] = 0.f;
          z = MFMA16(kf[jf][0], qf[0], z);
          st[jf] = MFMA16(kf[jf][1], qf[1], z);
        }
        __builtin_amdgcn_s_setprio(0);

        // softmax: P[q=cl][jf*16+quad*4+r] packed to bf16 IN REGISTERS.
        // w[jf] (2 u32 = 4 bf16) is exactly the 16x16x16 A-fragment
        // A[m=cl][k=quad*4+i] for the j-16-block (jl+jf*16).
        const bool diag = (jg0 + 32 > qb);
        uint2 w[2];
        #pragma unroll
        for (int jf = 0; jf < 2; ++jf) {
          float pv[4];
          if (diag) {
            const int qg = qb + cl;
            #pragma unroll
            for (int r = 0; r < 4; ++r) {
              const int jg = jg0 + jf * 16 + quad * 4 + r;
              pv[r] = (jg <= qg) ? EXP2F(st[jf][r]) : 0.f;
            }
          } else {
            #pragma unroll
            for (int r = 0; r < 4; ++r) pv[r] = EXP2F(st[jf][r]);
          }
          w[jf].x = pk2bf(pv[0], pv[1]);
          w[jf].y = pk2bf(pv[2], pv[3]);
        }
        const bf16x4 pf0 = __builtin_bit_cast(bf16x4, w[0]);
        const bf16x4 pf1 = __builtin_bit_cast(bf16x4, w[1]);

        // V fragments for 16x16x16 B[n=d][k=quad*4+i]: j = jl+jf*16+quad*4+i.
        // logical 16B slot = (jl>>3)+jf*2+(quad>>1), 8B half = quad&1;
        // phys slot = logical ^ (d&7) = logical ^ (cl&7)  [same involution].
        bf16x4 vf[2][4];
        #pragma unroll
        for (int jf = 0; jf < 2; ++jf) {
          const int slog = (jl >> 3) + jf * 2 + (quad >> 1);
          const int soff = ((slog ^ (cl & 7)) << 3) + ((quad & 1) << 2);
          #pragma unroll
          for (int dt = 0; dt < 4; ++dt) {
            const int d = dt * 16 + cl;
            vf[jf][dt] = *(const bf16x4*)&Vc[d * 64 + soff];
          }
        }

        __builtin_amdgcn_s_setprio(1);
        {
          f32x4 ls;
          #pragma unroll
          for (int r = 0; r < 4; ++r) ls[r] = 0.f;
          ls = MFMAK16(pf0, ones4, ls);
          ls = MFMAK16(pf1, ones4, ls);
          #pragma unroll
          for (int r = 0; r < 4; ++r) lr[r] += ls[r];
          #pragma unroll
          for (int dt = 0; dt < 4; ++dt) {
            oacc[dt] = MFMAK16(pf0, vf[0][dt], oacc[dt]);
            oacc[dt] = MFMAK16(pf1, vf[1][dt], oacc[dt]);
          }
        }
        __builtin_amdgcn_s_setprio(0);
      }
    }
  }

  // --- cross-split reduction: O = sum_sp O_sp, l = sum_sp l_sp (exact:
  // no-max softmax partials are pure sums). Scratch (61440B) aliases Ksm;
  // the barrier below orders it after the last K/V reads.
  __syncthreads();
  float* scr = reinterpret_cast<float*>(&Ksm[0][0][0]);
  if (sp > 0) {
    const int si = (((sp - 1) * 4 + g) * 64 + lane) * 20;
    #pragma unroll
    for (int dt = 0; dt < 4; ++dt)
      *(f32x4*)&scr[si + dt * 4] = oacc[dt];
    #pragma unroll
    for (int r = 0; r < 4; ++r) scr[si + 16 + r] = lr[r];
  }
  __syncthreads();
  if (sp == 0) {
    #pragma unroll
    for (int k = 0; k < 3; ++k) {
      const int si = ((k * 4 + g) * 64 + lane) * 20;
      #pragma unroll
      for (int dt = 0; dt < 4; ++dt) {
        const f32x4 o2 = *(const f32x4*)&scr[si + dt * 4];
        #pragma unroll
        for (int r = 0; r < 4; ++r) oacc[dt][r] += o2[r];
      }
      #pragma unroll
      for (int r = 0; r < 4; ++r) lr[r] += scr[si + 16 + r];
    }
    float inv[4];
    #pragma unroll
    for (int r = 0; r < 4; ++r) inv[r] = 1.f / lr[r];
    #pragma unroll
    for (int dt = 0; dt < 4; ++dt)
      #pragma unroll
      for (int r = 0; r < 4; ++r)
        CTX[(size_t)(b * 2048 + qb + quad * 4 + r) * 1024 +
            h * 64 + dt * 16 + cl] = f2bf(oacc[dt][r] * inv[r]);
  }
}

// ---------------------------------------------------------------------------
extern "C" void kernel_launch(void* const* d_in, const int* in_sizes, int n_in,
                              void* d_out, int out_size, void* d_ws, size_t ws_size,
                              hipStream_t stream)
{
  const float* x    = (const float*)d_in[0];
  const float* Wqkv = (const float*)d_in[1];
  const float* Wout = (const float*)d_in[2];
  const float* bout = (const float*)d_in[3];
  float* out = (float*)d_out;

  char* ws = (char*)d_ws;
  unsigned short* xb  = (unsigned short*)(ws);
  unsigned short* wqb = (unsigned short*)(ws + 8388608);
  unsigned short* wob = (unsigned short*)(ws + 14680064);
  unsigned short* Qb  = (unsigned short*)(ws + 16777216);
  unsigned short* Kb  = (unsigned short*)(ws + 25165824);
  unsigned short* Vt  = (unsigned short*)(ws + 33554432);
  unsigned short* CTX = (unsigned short*)(ws + 41943040);

  cast_bf16<<<dim3(8192), dim3(256), 0, stream>>>(x, Wqkv, Wout, xb, wqb, wob);

  // QKV projection: M=4096, N=3072, K=1024 -- 256^2 tile, 192 blocks
  gemm_qkv<<<dim3(192), dim3(512), 0, stream>>>(xb, wqb, Qb, Kb, Vt);

  // Flash attention: 1024 blocks (32 bh x 32 p'), 16 waves, 4-way j-split
  attn_mfma<<<dim3(1024), dim3(1024), 0, stream>>>(Qb, Kb, Vt, CTX);

  // Output projection: M=4096, N=1024, K=1024, + bias (proven 128^2 kernel)
  gemm_obt<<<dim3(8, 32), dim3(256), 0, stream>>>(CTX, wob, bout, out);
}

// Round 15
// 174.237 us; speedup vs baseline: 1.2426x; 1.0516x over previous
//
#include <hip/hip_runtime.h>
#include <cstdint>
#include <cstddef>

// MultiHeadAttention R25:
//   attn_mfma REVERTED to R22 (2-way j-split, 512 thr, 2 blocks/CU).
//   R24's 4-way split ran 1 block/CU: per-round barrier parked all 16
//   waves with no co-resident block -> attn 40 -> 48.5us. j-split only
//   wins while blocks/CU >= 2.
//   gemm_qkv unchanged (R22-measured 256^2 8-wave).
//   gemm_obt REWRITTEN: old version ran 256 blocks x 4 waves = 1 wave/SIMD
//   (zero latency hiding), 32 K-iters of BK=32, est ~55-60us for 1/3 of
//   qkv's FLOPs (obt+overhead ~73us constant across R0/R22/R24). New:
//   same 128x128 tile, 8 waves (2Mx4N, 64x32/wave, acc[4][2]), BK=64,
//   qkv's 4-phase/2-barrier loop scaled 1:1 (2 loads/stage-pair ->
//   vmcnt(2); queue invariant identical), LDS 64KB -> 2 blocks/CU =
//   16 waves/CU. Per-element K order unchanged (tiles asc, kk asc) ->
//   bitwise-identical output. launch_bounds(512,4) caps VGPR 128 (~100
//   expected; R23 lesson: one quadrant live at a time).
// ws layout (bytes):
//   xb @0 [4096][1024] bf16 | wqb @8388608 [3072][1024] | wob @14680064 [1024][1024]
//   Qb @16777216, Kb @25165824: [2][16][2048][64] bf16 (Qb = Q*log2e)
//   Vt @33554432: [2][16][64][2048] bf16 (transposed)
//   CTX @41943040 [4096][1024] bf16
// MFMA 16x16x32_bf16 frags: A[m=lane&15][k=quad*8+i], B[n=lane&15][k=quad*8+i],
// C/D[row=quad*4+reg][col=lane&15]. 16x16x16: k=quad*4+i, same C/D.
// Swapped operands -> D = C^T.

typedef __attribute__((ext_vector_type(8))) short bf16x8;
typedef __attribute__((ext_vector_type(4))) short bf16x4;
typedef __attribute__((ext_vector_type(4))) float f32x4;

#define LOG2E 1.44269504f

#define MFMA16(a, b, c) __builtin_amdgcn_mfma_f32_16x16x32_bf16((a), (b), (c), 0, 0, 0)

// K=16 bf16 MFMA: guard must only run in the DEVICE pass -- __has_builtin
// returns false for amdgcn builtins during hipcc's host pass (R10 lesson).
#if defined(__HIP_DEVICE_COMPILE__)
  #if __has_builtin(__builtin_amdgcn_mfma_f32_16x16x16bf16_1k)
    #define MFMAK16(a, b, c) __builtin_amdgcn_mfma_f32_16x16x16bf16_1k((a), (b), (c), 0, 0, 0)
  #elif __has_builtin(__builtin_amdgcn_mfma_f32_16x16x16_bf16)
    #define MFMAK16(a, b, c) __builtin_amdgcn_mfma_f32_16x16x16_bf16((a), (b), (c), 0, 0, 0)
  #else
    #error "no 16x16x16 bf16 MFMA builtin on device"
  #endif
#else
  #define MFMAK16(a, b, c) (c)   // host pass: parsed, never executed
#endif

#define GLDS16(g, s)                                                        \
  __builtin_amdgcn_global_load_lds(                                         \
      (const __attribute__((address_space(1))) void*)(g),                   \
      (__attribute__((address_space(3))) void*)(s), 16, 0, 0)

// Manual barrier: wait until <= N vector-memory ops outstanding, then barrier.
// ONLY valid when the loop's vmem traffic is exclusively the staged GLDS.
#define ASYNC_BAR(N) asm volatile("s_waitcnt vmcnt(" #N ")\n\ts_barrier" ::: "memory")
#define BAR() asm volatile("s_barrier" ::: "memory")

// Native 2^x: v_exp_f32 (gfx950 VOP1). Input already in log2 domain.
static __device__ __forceinline__ float exp2_hw(float x) {
  float r;
  asm("v_exp_f32 %0, %1" : "=v"(r) : "v"(x));
  return r;
}
#define EXP2F(x) exp2_hw(x)

static __device__ __forceinline__ unsigned short f2bf(float f) {  // RNE
  unsigned int u = __builtin_bit_cast(unsigned int, f);
  u += 0x7FFFu + ((u >> 16) & 1u);
  return (unsigned short)(u >> 16);
}

// pack two fp32 -> two bf16 (round-nearest) in one u32: 2 add + 1 perm
static __device__ __forceinline__ unsigned int pk2bf(float a, float b) {
  const unsigned int ua = __builtin_bit_cast(unsigned int, a) + 0x8000u;
  const unsigned int ub = __builtin_bit_cast(unsigned int, b) + 0x8000u;
  return __builtin_amdgcn_perm(ub, ua, 0x07060302);
}

// ---------------------------------------------------------------------------
__global__ __launch_bounds__(256) void cast_bf16(const float* __restrict__ x,
                                                 const float* __restrict__ wq,
                                                 const float* __restrict__ wo,
                                                 unsigned short* __restrict__ xb,
                                                 unsigned short* __restrict__ wqb,
                                                 unsigned short* __restrict__ wob)
{
  const int id = blockIdx.x * 256 + threadIdx.x;
  const float* src;
  unsigned short* dst;
  int off;
  if (id < 1048576)               { src = x;  dst = xb;  off = id; }
  else if (id < 1048576 + 786432) { src = wq; dst = wqb; off = id - 1048576; }
  else                            { src = wo; dst = wob; off = id - (1048576 + 786432); }
  float4 v = ((const float4*)src)[off];
  ushort4 o;
  o.x = f2bf(v.x); o.y = f2bf(v.y); o.z = f2bf(v.z); o.w = f2bf(v.w);
  ((ushort4*)dst)[off] = o;
}

// ---------------------------------------------------------------------------
// QKV GEMM (R22 version): 256x256 tile, BK=64, 512 threads = 8 waves
// (2M x 4N), per-wave 128x64 output (acc[8][4]).
// LDS 128 KiB: 2 buffers x (A 256x64 | B 256x64) bf16, rows of 128B split
// into 8x16B slots, phys_slot = logical_slot ^ (row & 7)   [FULL 3-bit XOR].
// 4 phases per K-tile, 16 MFMA each; ONE vmcnt(4) per K-tile.
// ---------------------------------------------------------------------------
#define MMAC(AF, BF, MS, NS)                                                       \
  do {                                                                             \
    __builtin_amdgcn_s_setprio(1);                                                 \
    if (swapped) {                                                                 \
      _Pragma("unroll")                                                            \
      for (int mt = 0; mt < 4; ++mt)                                               \
        _Pragma("unroll")                                                          \
        for (int nt = 0; nt < 2; ++nt) {                                           \
          acc[(MS)*4+mt][(NS)*2+nt] = MFMA16(BF[nt][0], AF[mt][0], acc[(MS)*4+mt][(NS)*2+nt]); \
          acc[(MS)*4+mt][(NS)*2+nt] = MFMA16(BF[nt][1], AF[mt][1], acc[(MS)*4+mt][(NS)*2+nt]); \
        }                                                                          \
    } else {                                                                       \
      _Pragma("unroll")                                                            \
      for (int mt = 0; mt < 4; ++mt)                                               \
        _Pragma("unroll")                                                          \
        for (int nt = 0; nt < 2; ++nt) {                                           \
          acc[(MS)*4+mt][(NS)*2+nt] = MFMA16(AF[mt][0], BF[nt][0], acc[(MS)*4+mt][(NS)*2+nt]); \
          acc[(MS)*4+mt][(NS)*2+nt] = MFMA16(AF[mt][1], BF[nt][1], acc[(MS)*4+mt][(NS)*2+nt]); \
        }                                                                          \
    }                                                                              \
    __builtin_amdgcn_s_setprio(0);                                                 \
  } while (0)

__global__ __launch_bounds__(512, 2) void gemm_qkv(const unsigned short* __restrict__ A,
                                                   const unsigned short* __restrict__ B,
                                                   unsigned short* __restrict__ Qb,
                                                   unsigned short* __restrict__ Kb,
                                                   unsigned short* __restrict__ Vt)
{
  // shorts: buf b: A @ b*32768 (256 rows x 64), B @ b*32768+16384. 128 KiB.
  __shared__ unsigned short pool[65536];

  const int tid  = threadIdx.x;
  const int wave = tid >> 6, lane = tid & 63, quad = lane >> 4, cl = lane & 15;
  const int wm = wave >> 2, wn = wave & 3;

  // Bijective XCD chunking: 192 blocks, 24/XCD covering a 4(mb) x 6(nb) chunk.
  const int bid = blockIdx.x;
  const int xcd = bid & 7, j = bid >> 3;
  const int mb = (xcd >> 1) * 4 + j / 6;
  const int nb = (xcd & 1) * 6 + j % 6;
  const int m0 = mb * 256, n0 = nb * 256;
  const int part = nb >> 2;                 // 0=Q 1=K 2=V
  const bool swapped = (part < 2);

  // --- staging: per GLDS16, wave covers 8 rows x 128B linearly.
  // lane l -> row r0+(l>>3), phys slot l&7. Pre-swizzled global source:
  // logical slot = phys ^ (row&7) = (l&7) ^ (l>>3)   [r0 is a multiple of 8]
  const int lrow = lane >> 3;
  const int sg   = (lane & 7) ^ lrow;

  auto stageA = [&](int h0, int buf, int k0) {
    #pragma unroll
    for (int ii = 0; ii < 2; ++ii) {
      const int r0 = h0 + wave * 16 + ii * 8;
      GLDS16(A + (size_t)(m0 + r0 + lrow) * 1024 + k0 + sg * 8,
             &pool[buf * 32768 + r0 * 64]);
    }
  };
  auto stageB = [&](int h0, int buf, int k0) {
    #pragma unroll
    for (int ii = 0; ii < 2; ++ii) {
      const int r0 = h0 + wave * 16 + ii * 8;
      GLDS16(B + (size_t)(n0 + r0 + lrow) * 1024 + k0 + sg * 8,
             &pool[buf * 32768 + 16384 + r0 * 64]);
    }
  };

  // --- fragment reads: row = 16-aligned base + cl -> row&7 == cl&7.
  // logical k-chunk (kk*4+quad) lives at phys slot (kk*4+quad) ^ (cl&7).
  const int rswz = cl & 7;
  auto loadA = [&](bf16x8 (&af)[4][2], int msub, int b) {
    const unsigned short* base = &pool[b * 32768];
    #pragma unroll
    for (int mt = 0; mt < 4; ++mt) {
      const int row = wm * 128 + msub * 64 + mt * 16 + cl;
      #pragma unroll
      for (int kk = 0; kk < 2; ++kk)
        af[mt][kk] = *(const bf16x8*)&base[row * 64 + ((kk * 4 + quad) ^ rswz) * 8];
    }
  };
  auto loadB = [&](bf16x8 (&bf)[2][2], int nsub, int b) {
    const unsigned short* base = &pool[b * 32768 + 16384];
    #pragma unroll
    for (int nt = 0; nt < 2; ++nt) {
      const int row = wn * 64 + nsub * 32 + nt * 16 + cl;
      #pragma unroll
      for (int kk = 0; kk < 2; ++kk)
        bf[nt][kk] = *(const bf16x8*)&base[row * 64 + ((kk * 4 + quad) ^ rswz) * 8];
    }
  };

  f32x4 acc[8][4];
  #pragma unroll
  for (int i = 0; i < 8; ++i)
    #pragma unroll
    for (int jj = 0; jj < 4; ++jj)
      #pragma unroll
      for (int r = 0; r < 4; ++r) acc[i][jj][r] = 0.f;

  // Prologue: all 4 half-tiles of tile0, then lo halves of tile1 (12 loads).
  stageB(0,   0, 0);
  stageA(0,   0, 0);
  stageB(128, 0, 0);
  stageA(128, 0, 0);
  stageB(0,   1, 64);
  stageA(0,   1, 64);

  #pragma unroll 1
  for (int t = 0; t < 16; ++t) {
    const int b = t & 1, bn = b ^ 1;
    const int kc  = (t + 1) * 64;
    const int kc2 = (t + 2) * 64;

    bf16x8 af[4][2], bfA[2][2], bfB[2][2];

    // P0: quadrant (0,0). vmcnt(4): guarantees all 4 halves of tile t
    // (newest needed = A-hi(t) @ (t-1)-P1; newer in flight = B-lo/A-lo(t+1)).
    if (t < 15) { ASYNC_BAR(4); } else { ASYNC_BAR(0); }
    loadA(af, 0, b);
    loadB(bfA, 0, b);
    if (t < 15) stageB(128, bn, kc);       // B-hi(t+1)
    MMAC(af, bfA, 0, 0);

    // P1: quadrant (0,1). No barrier needed: reads tile-t B (published at P0),
    // GLDS writes buffer bn (not being read).
    loadB(bfB, 1, b);
    if (t < 15) stageA(128, bn, kc);       // A-hi(t+1)
    MMAC(af, bfB, 0, 1);

    // P2: quadrant (1,1). Barrier: B-lo(t+2) overwrites B-lo(b) whose last
    // reads were P1 (other waves).
    BAR();
    loadA(af, 1, b);
    if (t < 14) stageB(0, b, kc2);         // B-lo(t+2)
    MMAC(af, bfB, 1, 1);

    // P3: quadrant (1,0), reuses bfA regs. Barrier: A-lo(t+2) overwrites
    // A-lo(b) whose last reads were P2 (wm=0 waves).
    BAR();
    if (t < 14) stageA(0, b, kc2);         // A-lo(t+2)
    MMAC(af, bfA, 1, 0);
  }
  // ASYNC_BAR(0) at t=15-P0 drained all staging: no GLDS in flight here.

  const int bb = m0 >> 11, ss = m0 & 2047;
  if (part < 2) {
    // Q/K (swapped: D=C^T): lane holds 4 consecutive d for one s -> ushort4
    unsigned short* dst = (part == 0) ? Qb : Kb;
    const float sc2 = (part == 0) ? LOG2E : 1.0f;
    const int npb = (n0 & 1023) + wn * 64;
    #pragma unroll
    for (int mt = 0; mt < 8; ++mt) {
      const int m = ss + wm * 128 + mt * 16 + cl;
      #pragma unroll
      for (int nt = 0; nt < 4; ++nt) {
        const int np = npb + nt * 16 + quad * 4;
        const int hh = np >> 6, d0 = np & 63;
        ushort4 pk;
        pk.x = f2bf(acc[mt][nt][0] * sc2);
        pk.y = f2bf(acc[mt][nt][1] * sc2);
        pk.z = f2bf(acc[mt][nt][2] * sc2);
        pk.w = f2bf(acc[mt][nt][3] * sc2);
        *(ushort4*)&dst[((size_t)(bb * 16 + hh) * 2048 + m) * 64 + d0] = pk;
      }
    }
  } else {
    // V (normal orientation): transpose through LDS (reuse pool),
    // trans[128][264] shorts per round; 2 rounds (wn pairs).
    unsigned short* trans = pool;
    #pragma unroll 1
    for (int r = 0; r < 2; ++r) {
      __syncthreads();
      if ((wn >> 1) == r) {
        #pragma unroll
        for (int mt = 0; mt < 8; ++mt) {
          const int s_l = wm * 128 + mt * 16 + quad * 4;
          #pragma unroll
          for (int nt = 0; nt < 4; ++nt) {
            const int n_l = (wn & 1) * 64 + nt * 16 + cl;
            ushort4 pk;
            pk.x = f2bf(acc[mt][nt][0]); pk.y = f2bf(acc[mt][nt][1]);
            pk.z = f2bf(acc[mt][nt][2]); pk.w = f2bf(acc[mt][nt][3]);
            *(ushort4*)&trans[n_l * 264 + s_l] = pk;
          }
        }
      }
      __syncthreads();
      const int row = tid >> 2, q4 = tid & 3;
      const int nv = (n0 & 1023) + r * 128 + row;
      const int hh = nv >> 6, d = nv & 63;
      unsigned short* drow = Vt + ((size_t)(bb * 16 + hh) * 64 + d) * 2048 + ss + q4 * 64;
      #pragma unroll
      for (int i = 0; i < 8; ++i)
        *(bf16x8*)(drow + i * 8) = *(const bf16x8*)&trans[row * 264 + q4 * 64 + i * 8];
    }
  }
}

// ---------------------------------------------------------------------------
// Out-projection R25: 128x128 tile, 512 threads = 8 waves (2M x 4N), wave
// owns 64x32 (acc[4][2]). BK=64, 16 K-tiles. qkv's 4-phase/2-barrier loop
// scaled 1:1: per stage-pair 2 GLDS/thread (A 1, B 1) -> vmcnt(2) at P0
// (queue: {t-lo(2), t-hi(2), t+1-lo(2)}; drains t fully). Phases stage
// B-hi(t+1) / A-hi(t+1) / B-lo(t+2) / A-lo(t+2). P2 BAR: B-lo last read P1
// (wn=0,1); P3 BAR: A-lo last read P2 (wm=0, msub=1 rows 32-63).
// LDS 2 x (A 128x64 | B 128x64) = 64KB -> 2 blocks/CU = 16 waves/CU.
// Same swizzle pair as qkv. Per-element K order = tiles asc, kk asc ->
// bitwise-identical to the old 32-iter BK=32 kernel.
// ---------------------------------------------------------------------------
__global__ __launch_bounds__(512, 4) void gemm_obt(const unsigned short* __restrict__ A,
                                                   const unsigned short* __restrict__ B,
                                                   const float* __restrict__ bias,
                                                   float* __restrict__ OutF)
{
  __shared__ unsigned short pool[32768];   // 2 x (A 8192 | B 8192) shorts

  const int tid  = threadIdx.x;
  const int wave = tid >> 6, lane = tid & 63, quad = lane >> 4, cl = lane & 15;
  const int wm = wave >> 2, wn = wave & 3;
  const int m0 = blockIdx.y * 128, n0 = blockIdx.x * 128;

  const int lrow = lane >> 3;
  const int sg   = (lane & 7) ^ lrow;

  auto stageA = [&](int h0, int buf, int k0) {
    const int r0 = h0 + wave * 8;
    GLDS16(A + (size_t)(m0 + r0 + lrow) * 1024 + k0 + sg * 8,
           &pool[buf * 16384 + r0 * 64]);
  };
  auto stageB = [&](int h0, int buf, int k0) {
    const int r0 = h0 + wave * 8;
    GLDS16(B + (size_t)(n0 + r0 + lrow) * 1024 + k0 + sg * 8,
           &pool[buf * 16384 + 8192 + r0 * 64]);
  };

  const int rswz = cl & 7;
  auto loadA = [&](bf16x8 (&af)[2][2], int msub, int b) {
    const unsigned short* base = &pool[b * 16384];
    #pragma unroll
    for (int mt = 0; mt < 2; ++mt) {
      const int row = wm * 64 + msub * 32 + mt * 16 + cl;
      #pragma unroll
      for (int kk = 0; kk < 2; ++kk)
        af[mt][kk] = *(const bf16x8*)&base[row * 64 + ((kk * 4 + quad) ^ rswz) * 8];
    }
  };
  auto loadB = [&](bf16x8 (&bf)[2], int nsub, int b) {
    const unsigned short* base = &pool[b * 16384 + 8192];
    const int row = wn * 32 + nsub * 16 + cl;
    #pragma unroll
    for (int kk = 0; kk < 2; ++kk)
      bf[kk] = *(const bf16x8*)&base[row * 64 + ((kk * 4 + quad) ^ rswz) * 8];
  };

  f32x4 acc[4][2];
  #pragma unroll
  for (int i = 0; i < 4; ++i)
    #pragma unroll
    for (int jj = 0; jj < 2; ++jj)
      #pragma unroll
      for (int r = 0; r < 4; ++r) acc[i][jj][r] = 0.f;

  // quadrant MFMA cluster: 2 mt x 1 nt x 2 kk (swapped: D = C^T)
  auto OMMA = [&](const bf16x8 (&af)[2][2], const bf16x8 (&bf)[2], int ms, int ns) {
    __builtin_amdgcn_s_setprio(1);
    #pragma unroll
    for (int mt = 0; mt < 2; ++mt) {
      acc[ms * 2 + mt][ns] = MFMA16(bf[0], af[mt][0], acc[ms * 2 + mt][ns]);
      acc[ms * 2 + mt][ns] = MFMA16(bf[1], af[mt][1], acc[ms * 2 + mt][ns]);
    }
    __builtin_amdgcn_s_setprio(0);
  };

  // Prologue: tile0 lo+hi, tile1 lo (6 GLDS).
  stageB(0,  0, 0);
  stageA(0,  0, 0);
  stageB(64, 0, 0);
  stageA(64, 0, 0);
  stageB(0,  1, 64);
  stageA(0,  1, 64);

  #pragma unroll 1
  for (int t = 0; t < 16; ++t) {
    const int b = t & 1, bn = b ^ 1;
    const int kc  = (t + 1) * 64;
    const int kc2 = (t + 2) * 64;

    bf16x8 af[2][2], bfA[2], bfB[2];

    // P0: vmcnt(2) drains tile t fully ({t-lo,t-hi}); t+1-lo stays in flight.
    if (t < 15) { ASYNC_BAR(2); } else { ASYNC_BAR(0); }
    loadA(af, 0, b);
    loadB(bfA, 0, b);
    if (t < 15) stageB(64, bn, kc);        // B-hi(t+1)
    OMMA(af, bfA, 0, 0);

    // P1: no barrier (reads tile-t B resident since P0; GLDS writes bn).
    loadB(bfB, 1, b);
    if (t < 15) stageA(64, bn, kc);        // A-hi(t+1)
    OMMA(af, bfB, 0, 1);

    // P2: barrier -- B-lo(t+2) overwrites B-lo(b), last read P1 (wn=0,1).
    BAR();
    loadA(af, 1, b);
    if (t < 14) stageB(0, b, kc2);         // B-lo(t+2)
    OMMA(af, bfB, 1, 1);

    // P3: barrier -- A-lo(t+2) overwrites A-lo(b), last read P2 (wm=0).
    BAR();
    if (t < 14) stageA(0, b, kc2);         // A-lo(t+2)
    OMMA(af, bfA, 1, 0);
  }

  #pragma unroll
  for (int mt = 0; mt < 4; ++mt) {
    const int m = m0 + wm * 64 + mt * 16 + cl;
    #pragma unroll
    for (int nt = 0; nt < 2; ++nt) {
      const int n = n0 + wn * 32 + nt * 16 + quad * 4;
      const float4 bv = *(const float4*)(bias + n);
      float4 o;
      o.x = acc[mt][nt][0] + bv.x; o.y = acc[mt][nt][1] + bv.y;
      o.z = acc[mt][nt][2] + bv.z; o.w = acc[mt][nt][3] + bv.w;
      *(float4*)&OutF[(size_t)m * 1024 + n] = o;
    }
  }
}

// ---------------------------------------------------------------------------
// Flash attention (R22 version): 8-wave blocks (512 thr), 4 groups
// (G=4p'+g, uniform nch = p'+1), 2-way j-split: wave (g = w&3, s = w>>2)
// computes chunks 2t+s. KVBLK=128 rounds, shared dbuf staging, ONE
// vmcnt(0)+barrier per round. P-in-registers K=16 PV. End: s=1 partials ->
// LDS scratch (aliased over Ksm), s=0 adds + normalizes + writes CTX.
// LDS: Ksm 32KB + Vsm 32KB = 65536B -> 2 blocks/CU (16 waves/CU).
// ---------------------------------------------------------------------------
__global__ __launch_bounds__(512) void attn_mfma(const unsigned short* __restrict__ Qb,
                                                 const unsigned short* __restrict__ Kb,
                                                 const unsigned short* __restrict__ Vt,
                                                 unsigned short* __restrict__ CTX)
{
  __shared__ unsigned short Ksm[2][2][64 * 64];   // [round buf][sub][64 rows x 128B]
  __shared__ unsigned short Vsm[2][2][64 * 64];

  const int tid  = threadIdx.x;
  const int wave = tid >> 6, lane = tid & 63, quad = lane >> 4, cl = lane & 15;
  const int g = wave & 3, sp = wave >> 2;         // group-slot, j-split index

  const int L  = blockIdx.x;
  const int bh = 4 * (L & 7) + ((L >> 3) & 3);    // XCD-affine: 4 bh per XCD
  const int b  = bh >> 4, h = bh & 15;
  const int pp = 31 - (L >> 5);                   // 0..31, big-work-first
  const int G  = pp * 4 + g;                      // q-group 0..127
  const int qb = G * 16;
  const size_t base = (size_t)bh * (2048 * 64);

  bf16x8 qf[2];
  #pragma unroll
  for (int dk = 0; dk < 2; ++dk)
    qf[dk] = *(const bf16x8*)(Qb + base + (size_t)(qb + cl) * 64 + dk * 32 + quad * 8);

  f32x4 oacc[4];
  #pragma unroll
  for (int dt = 0; dt < 4; ++dt)
    #pragma unroll
    for (int r = 0; r < 4; ++r) oacc[dt][r] = 0.f;
  float lr[4] = {};

  bf16x4 ones4;
  #pragma unroll
  for (int k = 0; k < 4; ++k) ones4[k] = (short)0x3F80;

  const int lrow  = lane >> 3;
  const int lslot = (lane & 7) ^ lrow;
  const int nch = pp + 1;                          // 64-chunks: 1..32
  const int nrd = (nch + 1) >> 1;                  // 128-rounds: 1..16

  // Stage one 64-j sub-chunk, 8 waves x 8 rows each (row = wave*8 + lrow).
  auto stageKV = [&](int ch, int buf, int sub) {
    const int j64 = ch * 64;
    const int r0 = wave * 8;
    GLDS16(Kb + base + (size_t)(j64 + r0 + lrow) * 64 + lslot * 8,
           &Ksm[buf][sub][r0 * 64]);
    GLDS16(Vt + base + (size_t)(r0 + lrow) * 2048 + j64 + lslot * 8,
           &Vsm[buf][sub][r0 * 64]);
  };

  // Prologue: round 0 = chunks 0,1 (chunk 1 always within the 2048-row
  // arrays; if unused (pp=0) it is drained by the round-0 ASYNC_BAR(0)).
  stageKV(0, 0, 0);
  stageKV(1, 0, 1);

  #pragma unroll 1
  for (int t = 0; t < nrd; ++t) {
    // Drain round t's 4 GLDS (issued a full round ago; K/V L2-resident) and
    // sync. Barrier also proves all waves are past round t-1's reads of
    // buf[(t+1)&1] -> safe to overwrite.
    ASYNC_BAR(0);
    if (t + 1 < nrd) {
      stageKV(2 * t + 2, (t + 1) & 1, 0);
      stageKV(2 * t + 3, (t + 1) & 1, 1);
    }

    // This wave computes ONLY chunk 2t+sp for its group.
    {
      const int ch = 2 * t + sp;
      const unsigned short* Kc = Ksm[t & 1][sp];
      const unsigned short* Vc = Vsm[t & 1][sp];
      const int j64c = ch * 64;

      #pragma unroll
      for (int jli = 0; jli < 2; ++jli) {
        const int jg0 = j64c + jli * 32;
        if (jg0 > qb + 15) continue;               // causal skip (covers ch>=nch too)
        const int jl = jli * 32;

        bf16x8 kf[2][2];
        #pragma unroll
        for (int jf = 0; jf < 2; ++jf)
          #pragma unroll
          for (int dk = 0; dk < 2; ++dk) {
            const int jrow = jl + jf * 16 + cl;
            const int slot = (dk * 4 + quad) ^ (cl & 7);
            kf[jf][dk] = *(const bf16x8*)&Kc[jrow * 64 + slot * 8];
          }

        f32x4 st[2];
        __builtin_amdgcn_s_setprio(1);
        #pragma unroll
        for (int jf = 0; jf < 2; ++jf) {
          f32x4 z;
          #pragma unroll
          for (int r = 0; r < 4; ++r) z[r] = 0.f;
          z = MFMA16(kf[jf][0], qf[0], z);
          st[jf] = MFMA16(kf[jf][1], qf[1], z);
        }
        __builtin_amdgcn_s_setprio(0);

        // softmax: P[q=cl][jf*16+quad*4+r] packed to bf16 IN REGISTERS.
        // w[jf] (2 u32 = 4 bf16) is exactly the 16x16x16 A-fragment
        // A[m=cl][k=quad*4+i] for the j-16-block (jl+jf*16).
        const bool diag = (jg0 + 32 > qb);
        uint2 w[2];
        #pragma unroll
        for (int jf = 0; jf < 2; ++jf) {
          float pv[4];
          if (diag) {
            const int qg = qb + cl;
            #pragma unroll
            for (int r = 0; r < 4; ++r) {
              const int jg = jg0 + jf * 16 + quad * 4 + r;
              pv[r] = (jg <= qg) ? EXP2F(st[jf][r]) : 0.f;
            }
          } else {
            #pragma unroll
            for (int r = 0; r < 4; ++r) pv[r] = EXP2F(st[jf][r]);
          }
          w[jf].x = pk2bf(pv[0], pv[1]);
          w[jf].y = pk2bf(pv[2], pv[3]);
        }
        const bf16x4 pf0 = __builtin_bit_cast(bf16x4, w[0]);
        const bf16x4 pf1 = __builtin_bit_cast(bf16x4, w[1]);

        // V fragments for 16x16x16 B[n=d][k=quad*4+i]: j = jl+jf*16+quad*4+i.
        // logical 16B slot = (jl>>3)+jf*2+(quad>>1), 8B half = quad&1;
        // phys slot = logical ^ (d&7) = logical ^ (cl&7)  [same involution].
        bf16x4 vf[2][4];
        #pragma unroll
        for (int jf = 0; jf < 2; ++jf) {
          const int slog = (jl >> 3) + jf * 2 + (quad >> 1);
          const int soff = ((slog ^ (cl & 7)) << 3) + ((quad & 1) << 2);
          #pragma unroll
          for (int dt = 0; dt < 4; ++dt) {
            const int d = dt * 16 + cl;
            vf[jf][dt] = *(const bf16x4*)&Vc[d * 64 + soff];
          }
        }

        __builtin_amdgcn_s_setprio(1);
        {
          f32x4 ls;
          #pragma unroll
          for (int r = 0; r < 4; ++r) ls[r] = 0.f;
          ls = MFMAK16(pf0, ones4, ls);
          ls = MFMAK16(pf1, ones4, ls);
          #pragma unroll
          for (int r = 0; r < 4; ++r) lr[r] += ls[r];
          #pragma unroll
          for (int dt = 0; dt < 4; ++dt) {
            oacc[dt] = MFMAK16(pf0, vf[0][dt], oacc[dt]);
            oacc[dt] = MFMAK16(pf1, vf[1][dt], oacc[dt]);
          }
        }
        __builtin_amdgcn_s_setprio(0);
      }
    }
  }

  // --- cross-split reduction: O = O_s0 + O_s1, l = l_s0 + l_s1 (exact:
  // no-max softmax partials are pure sums). Scratch aliases Ksm; the
  // barrier below orders it after the last K/V reads.
  __syncthreads();
  float* scr = reinterpret_cast<float*>(&Ksm[0][0][0]);   // 4*64*20*4B = 20KB
  const int si = (g * 64 + lane) * 20;
  if (sp == 1) {
    #pragma unroll
    for (int dt = 0; dt < 4; ++dt)
      *(f32x4*)&scr[si + dt * 4] = oacc[dt];
    #pragma unroll
    for (int r = 0; r < 4; ++r) scr[si + 16 + r] = lr[r];
  }
  __syncthreads();
  if (sp == 0) {
    #pragma unroll
    for (int dt = 0; dt < 4; ++dt) {
      const f32x4 o2 = *(const f32x4*)&scr[si + dt * 4];
      #pragma unroll
      for (int r = 0; r < 4; ++r) oacc[dt][r] += o2[r];
    }
    float inv[4];
    #pragma unroll
    for (int r = 0; r < 4; ++r) inv[r] = 1.f / (lr[r] + scr[si + 16 + r]);
    #pragma unroll
    for (int dt = 0; dt < 4; ++dt)
      #pragma unroll
      for (int r = 0; r < 4; ++r)
        CTX[(size_t)(b * 2048 + qb + quad * 4 + r) * 1024 +
            h * 64 + dt * 16 + cl] = f2bf(oacc[dt][r] * inv[r]);
  }
}

// ---------------------------------------------------------------------------
extern "C" void kernel_launch(void* const* d_in, const int* in_sizes, int n_in,
                              void* d_out, int out_size, void* d_ws, size_t ws_size,
                              hipStream_t stream)
{
  const float* x    = (const float*)d_in[0];
  const float* Wqkv = (const float*)d_in[1];
  const float* Wout = (const float*)d_in[2];
  const float* bout = (const float*)d_in[3];
  float* out = (float*)d_out;

  char* ws = (char*)d_ws;
  unsigned short* xb  = (unsigned short*)(ws);
  unsigned short* wqb = (unsigned short*)(ws + 8388608);
  unsigned short* wob = (unsigned short*)(ws + 14680064);
  unsigned short* Qb  = (unsigned short*)(ws + 16777216);
  unsigned short* Kb  = (unsigned short*)(ws + 25165824);
  unsigned short* Vt  = (unsigned short*)(ws + 33554432);
  unsigned short* CTX = (unsigned short*)(ws + 41943040);

  cast_bf16<<<dim3(8192), dim3(256), 0, stream>>>(x, Wqkv, Wout, xb, wqb, wob);

  // QKV projection: M=4096, N=3072, K=1024 -- 256^2 tile, 192 blocks
  gemm_qkv<<<dim3(192), dim3(512), 0, stream>>>(xb, wqb, Qb, Kb, Vt);

  // Flash attention: 1024 blocks (32 bh x 32 p'), 8 waves, 2-way j-split
  attn_mfma<<<dim3(1024), dim3(512), 0, stream>>>(Qb, Kb, Vt, CTX);

  // Output projection: M=4096, N=1024, K=1024, + bias -- 128^2 tile,
  // 8 waves, BK=64, 2 blocks/CU (was 4 waves / 1 wave/SIMD / BK=32)
  gemm_obt<<<dim3(8, 32), dim3(512), 0, stream>>>(CTX, wob, bout, out);
}